// Round 2
// baseline (3506.387 us; speedup 1.0000x reference)
//
#include <hip/hip_runtime.h>
#include <math.h>

// Problem constants
#define NB   16
#define NC   256
#define NP   4096      // 64*64 spatial
#define NHD  8         // heads
#define FD   64        // dim head
#define HID  512       // NHD*FD
#define OC3  1536      // 3*HID
#define NG   32        // groups (C/8)
#define CPG  8         // channels per group
#define GEPS 1e-5f

// ----- per-batch workspace layout (floats), total ~28 MB -----
static constexpr size_t OFF_QKVB  = 0;                                    // [OC3][NP]      (reused per batch)
static constexpr size_t OFF_CTXP  = OFF_QKVB + (size_t)OC3*NP;            // [4][NHD][FD][FD]
static constexpr size_t OFF_CTX   = OFF_CTXP + (size_t)4*NHD*FD*FD;       // [NHD][FD][FD]
static constexpr size_t OFF_W2BT  = OFF_CTX  + (size_t)NHD*FD*FD;         // [HID][NC]
static constexpr size_t OFF_WTQKV = OFF_W2BT + (size_t)HID*NC;            // [NC][OC3]
static constexpr size_t OFF_ACDC  = OFF_WTQKV+ (size_t)NC*OC3;            // ac[NB][NC], dc[NB][NC]
static constexpr size_t OFF_GN1   = OFF_ACDC + (size_t)2*NB*NC;           // mu[512], rstd[512]
static constexpr size_t OFF_GN2   = OFF_GN1  + (size_t)2*NB*NG;

// ===================== GroupNorm stats: one block per (b,g) =====================
__global__ __launch_bounds__(256) void gn_stats_kernel(const float* __restrict__ x,
                                                       float* __restrict__ mu,
                                                       float* __restrict__ rstd) {
    int bg = blockIdx.x;                       // b*NG + g ; group data contiguous 8*4096 floats
    const float4* b4 = (const float4*)(x + (size_t)bg * CPG * NP);
    int t = threadIdx.x;
    float s = 0.f, sq = 0.f;
    #pragma unroll
    for (int i = 0; i < 32; ++i) {             // 8192 float4 / 256 threads
        float4 v = b4[t + i * 256];
        s  += v.x + v.y + v.z + v.w;
        sq += v.x*v.x + v.y*v.y + v.z*v.z + v.w*v.w;
    }
    for (int off = 32; off; off >>= 1) { s += __shfl_down(s, off); sq += __shfl_down(sq, off); }
    __shared__ float ss[4], ssq[4];
    int wid = t >> 6, lane = t & 63;
    if (lane == 0) { ss[wid] = s; ssq[wid] = sq; }
    __syncthreads();
    if (t == 0) {
        float S  = ss[0] + ss[1] + ss[2] + ss[3];
        float SQ = ssq[0] + ssq[1] + ssq[2] + ssq[3];
        const float inv = 1.f / (float)(CPG * NP);
        float m = S * inv;
        float var = SQ * inv - m * m;
        mu[bg] = m;
        rstd[bg] = rsqrtf(var + GEPS);
    }
}

// ===================== GN1 -> per (b,c) affine coefs =====================
__global__ void gn1_coefs_kernel(const float* __restrict__ mu, const float* __restrict__ rstd,
                                 const float* __restrict__ w, const float* __restrict__ bias,
                                 float* __restrict__ ac, float* __restrict__ dc) {
    int i = blockIdx.x * 256 + threadIdx.x;    // NB*NC = 4096
    if (i >= NB * NC) return;
    int b = i / NC, c = i % NC;
    int g = c / CPG;
    float m = mu[b * NG + g], r = rstd[b * NG + g];
    float a = r * w[c];
    ac[i] = a;
    dc[i] = bias[c] - m * a;
}

// ===================== generic 32x32 transpose =====================
__global__ void transpose_kernel(const float* __restrict__ src, float* __restrict__ dst,
                                 int M, int N) {   // src[M][N] -> dst[N][M]
    __shared__ float tile[32][33];
    int bx = blockIdx.x * 32, by = blockIdx.y * 32;
    int tx = threadIdx.x, ty = threadIdx.y;        // 32 x 8
    #pragma unroll
    for (int i = 0; i < 32; i += 8)
        tile[ty + i][tx] = src[(size_t)(by + ty + i) * N + bx + tx];
    __syncthreads();
    #pragma unroll
    for (int i = 0; i < 32; i += 8)
        dst[(size_t)(bx + ty + i) * M + by + tx] = tile[tx][ty + i];
}

// ===================== fp32 tiled GEMM (single batch): C = At^T * B (+affine on B) (+bias)
// At: [K][Mtot] (row stride Mtot), B: [K][NP], C: [Mtot][NP]
template <bool AFFINE, bool BIAS>
__global__ __launch_bounds__(256) void gemm_kernel(
        const float* __restrict__ At, const float* __restrict__ Bb,
        const float* __restrict__ acg, const float* __restrict__ dcg,
        const float* __restrict__ bias, float* __restrict__ Cb,
        int K, int Mtot) {
    __shared__ float As[32][128];
    __shared__ float Bs[32][128];
    const int tid = threadIdx.x;
    const int tx = tid & 15, ty = tid >> 4;
    const int m0 = blockIdx.y * 128, n0 = blockIdx.x * 128;
    float acc[8][8] = {};

    for (int k0 = 0; k0 < K; k0 += 32) {
        #pragma unroll
        for (int j = 0; j < 4; ++j) {
            int idx = tid + j * 256;              // 0..1023
            int r = idx >> 5, c4 = idx & 31;
            float4 v = *(const float4*)(At + (size_t)(k0 + r) * Mtot + m0 + c4 * 4);
            *(float4*)&As[r][c4 * 4] = v;
        }
        #pragma unroll
        for (int j = 0; j < 4; ++j) {
            int idx = tid + j * 256;
            int r = idx >> 5, c4 = idx & 31;
            float4 v = *(const float4*)(Bb + (size_t)(k0 + r) * NP + n0 + c4 * 4);
            if (AFFINE) {
                float a = acg[k0 + r], d = dcg[k0 + r];
                v.x = fmaf(v.x, a, d); v.y = fmaf(v.y, a, d);
                v.z = fmaf(v.z, a, d); v.w = fmaf(v.w, a, d);
            }
            *(float4*)&Bs[r][c4 * 4] = v;
        }
        __syncthreads();
        #pragma unroll
        for (int kk = 0; kk < 32; ++kk) {
            float a[8], bv[8];
            *(float4*)&a[0]  = *(const float4*)&As[kk][ty * 8];
            *(float4*)&a[4]  = *(const float4*)&As[kk][ty * 8 + 4];
            *(float4*)&bv[0] = *(const float4*)&Bs[kk][tx * 8];
            *(float4*)&bv[4] = *(const float4*)&Bs[kk][tx * 8 + 4];
            #pragma unroll
            for (int i = 0; i < 8; ++i)
                #pragma unroll
                for (int j = 0; j < 8; ++j)
                    acc[i][j] = fmaf(a[i], bv[j], acc[i][j]);
        }
        __syncthreads();
    }
    #pragma unroll
    for (int i = 0; i < 8; ++i) {
        int m = m0 + ty * 8 + i;
        float bi = BIAS ? bias[m] : 0.f;
        float4 v0 = {acc[i][0]+bi, acc[i][1]+bi, acc[i][2]+bi, acc[i][3]+bi};
        float4 v1 = {acc[i][4]+bi, acc[i][5]+bi, acc[i][6]+bi, acc[i][7]+bi};
        *(float4*)(Cb + (size_t)m * NP + n0 + tx * 8)     = v0;
        *(float4*)(Cb + (size_t)m * NP + n0 + tx * 8 + 4) = v1;
    }
}

// ===================== softmax over feature dim (q), in-place, *scale (per batch) ==========
__global__ __launch_bounds__(256) void softmax_q_b(float* __restrict__ qkv) {
    int gid = blockIdx.x * 256 + threadIdx.x;     // NHD*NP = 32768
    int p = gid & (NP - 1);
    int h = gid >> 12;
    float* base = qkv + (size_t)h * FD * NP + p;
    float v[FD];
    float mx = -INFINITY;
    #pragma unroll
    for (int f = 0; f < FD; ++f) { v[f] = base[(size_t)f * NP]; mx = fmaxf(mx, v[f]); }
    float s = 0.f;
    #pragma unroll
    for (int f = 0; f < FD; ++f) { v[f] = __expf(v[f] - mx); s += v[f]; }
    float inv = 0.125f / s;                       // DIM_HEAD^-0.5 folded in
    #pragma unroll
    for (int f = 0; f < FD; ++f) base[(size_t)f * NP] = v[f] * inv;
}

// ===================== softmax over spatial dim (k), in-place (per batch) ==========
__global__ __launch_bounds__(256) void softmax_k_b(float* __restrict__ qkv) {
    int row = blockIdx.x;                          // HID = 512 rows
    float* base = qkv + (size_t)(HID + row) * NP;
    int t = threadIdx.x;
    float4 v[4];
    float mx = -INFINITY;
    #pragma unroll
    for (int i = 0; i < 4; ++i) {
        v[i] = *(float4*)(base + t * 4 + i * 1024);
        mx = fmaxf(mx, fmaxf(fmaxf(v[i].x, v[i].y), fmaxf(v[i].z, v[i].w)));
    }
    for (int off = 32; off; off >>= 1) mx = fmaxf(mx, __shfl_down(mx, off));
    __shared__ float sm[4], ssum[4];
    int wid = t >> 6, lane = t & 63;
    if (lane == 0) sm[wid] = mx;
    __syncthreads();
    mx = fmaxf(fmaxf(sm[0], sm[1]), fmaxf(sm[2], sm[3]));
    float s = 0.f;
    #pragma unroll
    for (int i = 0; i < 4; ++i) {
        v[i].x = __expf(v[i].x - mx); v[i].y = __expf(v[i].y - mx);
        v[i].z = __expf(v[i].z - mx); v[i].w = __expf(v[i].w - mx);
        s += v[i].x + v[i].y + v[i].z + v[i].w;
    }
    for (int off = 32; off; off >>= 1) s += __shfl_down(s, off);
    if (lane == 0) ssum[wid] = s;
    __syncthreads();
    s = ssum[0] + ssum[1] + ssum[2] + ssum[3];
    float inv = 1.f / s;
    #pragma unroll
    for (int i = 0; i < 4; ++i) {
        v[i].x *= inv; v[i].y *= inv; v[i].z *= inv; v[i].w *= inv;
        *(float4*)(base + t * 4 + i * 1024) = v[i];
    }
}

// ===================== context = k_s @ v^T per head, p-sliced x4 (per batch) ==========
__global__ __launch_bounds__(256) void context_b(const float* __restrict__ qkv,
                                                 float* __restrict__ ctxp) {
    int s = blockIdx.x, h = blockIdx.y;           // 4 x 8
    const float* kbase = qkv + (size_t)(HID   + h*FD)*NP + s*1024;
    const float* vbase = qkv + (size_t)(2*HID + h*FD)*NP + s*1024;
    __shared__ float Ks[64][68];
    __shared__ float Vs[64][68];
    int t = threadIdx.x;
    int tx = t & 15, ty = t >> 4;
    float acc[4][4] = {};
    for (int p0 = 0; p0 < 1024; p0 += 64) {
        #pragma unroll
        for (int j = 0; j < 4; ++j) {
            int idx = t + j * 256;                // 1024 float4 slots
            int r = idx >> 4, c4 = idx & 15;
            *(float4*)&Ks[r][c4 * 4] = *(const float4*)(kbase + (size_t)r * NP + p0 + c4 * 4);
            *(float4*)&Vs[r][c4 * 4] = *(const float4*)(vbase + (size_t)r * NP + p0 + c4 * 4);
        }
        __syncthreads();
        #pragma unroll
        for (int pp = 0; pp < 64; pp += 4) {
            float4 a[4], bv[4];
            #pragma unroll
            for (int i = 0; i < 4; ++i) a[i]  = *(float4*)&Ks[ty * 4 + i][pp];
            #pragma unroll
            for (int j = 0; j < 4; ++j) bv[j] = *(float4*)&Vs[tx * 4 + j][pp];
            #pragma unroll
            for (int i = 0; i < 4; ++i)
                #pragma unroll
                for (int j = 0; j < 4; ++j)
                    acc[i][j] += a[i].x*bv[j].x + a[i].y*bv[j].y + a[i].z*bv[j].z + a[i].w*bv[j].w;
        }
        __syncthreads();
    }
    float* outp = ctxp + ((size_t)s * NHD + h) * FD * FD;
    #pragma unroll
    for (int i = 0; i < 4; ++i)
        *(float4*)(outp + (size_t)(ty * 4 + i) * FD + tx * 4) = *(float4*)&acc[i][0];
}

__global__ void ctx_reduce_b(const float* __restrict__ ctxp, float* __restrict__ ctx) {
    int i = blockIdx.x * 256 + threadIdx.x;       // 8192 float4
    const float4* p = (const float4*)ctxp;
    float4 a = p[i], b = p[i + 8192], c = p[i + 16384], d = p[i + 24576];
    float4 r = {a.x+b.x+c.x+d.x, a.y+b.y+c.y+d.y, a.z+b.z+c.z+d.z, a.w+b.w+c.w+d.w};
    ((float4*)ctx)[i] = r;
}

// ===================== fold: w2bt[h*64+f][o] = sum_e out_w[o][h*64+e]*ctx[h,f,e] (per batch) ==========
__global__ __launch_bounds__(256) void fold_b(const float* __restrict__ out_w,
                                              const float* __restrict__ ctx,
                                              float* __restrict__ w2bt) {
    int h = blockIdx.x;                            // NHD = 8
    __shared__ float Cs[FD][FD];                   // [f][e]
    int t = threadIdx.x;
    const float* cbase = ctx + (size_t)h * FD * FD;
    #pragma unroll
    for (int j = 0; j < 16; ++j) ((float*)Cs)[t + j * 256] = cbase[t + j * 256];
    __syncthreads();
    float wr[64];
    const float* wrow = out_w + (size_t)t * HID + h * FD;   // thread t owns output channel o=t
    #pragma unroll
    for (int e = 0; e < 64; ++e) wr[e] = wrow[e];
    float* obase = w2bt + (size_t)h * FD * NC;
    for (int f = 0; f < 64; ++f) {
        float sacc = 0.f;
        #pragma unroll
        for (int e = 0; e < 64; ++e) sacc = fmaf(wr[e], Cs[f][e], sacc);
        obase[(size_t)f * NC + t] = sacc;
    }
}

// ===================== GN2 apply in-place on d_out =====================
__global__ void gn2_apply_kernel(float* __restrict__ out, const float* __restrict__ mu,
                                 const float* __restrict__ rstd, const float* __restrict__ w,
                                 const float* __restrict__ bias) {
    int i = blockIdx.x * 256 + threadIdx.x;        // 4194304 float4
    float4* p = (float4*)out;
    float4 v = p[i];
    size_t e0 = (size_t)i * 4;
    int cidx = (int)((e0 / NP) % NC);
    int bg   = (int)(e0 / ((size_t)CPG * NP));
    float m = mu[bg], r = rstd[bg];
    float a = r * w[cidx];
    float d = bias[cidx] - m * a;
    v.x = fmaf(v.x, a, d); v.y = fmaf(v.y, a, d);
    v.z = fmaf(v.z, a, d); v.w = fmaf(v.w, a, d);
    p[i] = v;
}

// ===================== launch =====================
extern "C" void kernel_launch(void* const* d_in, const int* in_sizes, int n_in,
                              void* d_out, int out_size, void* d_ws, size_t ws_size,
                              hipStream_t stream) {
    const float* x     = (const float*)d_in[0];
    const float* gn1_w = (const float*)d_in[1];
    const float* gn1_b = (const float*)d_in[2];
    const float* qkv_w = (const float*)d_in[3];
    const float* out_w = (const float*)d_in[4];
    const float* out_b = (const float*)d_in[5];
    const float* gn2_w = (const float*)d_in[6];
    const float* gn2_b = (const float*)d_in[7];
    float* out = (float*)d_out;

    float* ws    = (float*)d_ws;
    float* qkvb  = ws + OFF_QKVB;
    float* ctxp  = ws + OFF_CTXP;
    float* ctx   = ws + OFF_CTX;
    float* w2bt  = ws + OFF_W2BT;
    float* wtqkv = ws + OFF_WTQKV;
    float* ac    = ws + OFF_ACDC;
    float* dc    = ac + (size_t)NB * NC;
    float* mu1   = ws + OFF_GN1;
    float* rstd1 = mu1 + NB * NG;
    float* mu2   = ws + OFF_GN2;
    float* rstd2 = mu2 + NB * NG;

    // 1. GN1 stats + affine coefs (all batches)
    gn_stats_kernel<<<NB * NG, 256, 0, stream>>>(x, mu1, rstd1);
    gn1_coefs_kernel<<<16, 256, 0, stream>>>(mu1, rstd1, gn1_w, gn1_b, ac, dc);

    // 2. transpose qkv_w -> [K=256][M=1536]
    transpose_kernel<<<dim3(256 / 32, 1536 / 32), dim3(32, 8), 0, stream>>>(qkv_w, wtqkv, 1536, 256);

    // 3..7 per batch (scratch reused; stream order serializes)
    for (int b = 0; b < NB; ++b) {
        const float* xb = x + (size_t)b * NC * NP;
        float* outb = out + (size_t)b * NC * NP;
        gemm_kernel<true, false><<<dim3(32, 12), 256, 0, stream>>>(
            wtqkv, xb, ac + (size_t)b * NC, dc + (size_t)b * NC, nullptr, qkvb, 256, OC3);
        softmax_q_b<<<128, 256, 0, stream>>>(qkvb);
        softmax_k_b<<<512, 256, 0, stream>>>(qkvb);
        context_b<<<dim3(4, NHD), 256, 0, stream>>>(qkvb, ctxp);
        ctx_reduce_b<<<32, 256, 0, stream>>>(ctxp, ctx);
        fold_b<<<NHD, 256, 0, stream>>>(out_w, ctx, w2bt);
        gemm_kernel<false, true><<<dim3(32, 2), 256, 0, stream>>>(
            w2bt, qkvb, nullptr, nullptr, out_b, outb, HID, NC);
    }

    // 8. GN2 (stats on d_out, apply in-place)
    gn_stats_kernel<<<NB * NG, 256, 0, stream>>>(out, mu2, rstd2);
    gn2_apply_kernel<<<16384, 256, 0, stream>>>(out, mu2, rstd2, gn2_w, gn2_b);
}

// Round 4
// 968.426 us; speedup vs baseline: 3.6207x; 3.6207x over previous
//
#include <hip/hip_runtime.h>
#include <math.h>

#define NB   16
#define NC   256
#define NP   4096
#define NHD  8
#define FD   64
#define HID  512
#define OC3  1536
#define NG   32
#define CPG  8
#define GEPS 1e-5f

typedef __attribute__((ext_vector_type(8))) short bf16x8;
typedef __attribute__((ext_vector_type(4))) float f32x4;

#define MFMA_BF16(a, b, c) __builtin_amdgcn_mfma_f32_16x16x32_bf16(a, b, c, 0, 0, 0)

__device__ __forceinline__ uint bf16_rne(float v) {
    uint u = __float_as_uint(v);
    return (u + 0x7FFFu + ((u >> 16) & 1u)) >> 16;
}
__device__ __forceinline__ void split2(float v, uint& h, uint& l) {
    h = bf16_rne(v);
    float hf = __uint_as_float(h << 16);
    l = bf16_rne(v - hf);
}

// ===================== GroupNorm stats: one block per (b,g) =====================
__global__ __launch_bounds__(256) void gn_stats_kernel(const float* __restrict__ x,
                                                       float* __restrict__ mu,
                                                       float* __restrict__ rstd) {
    int bg = blockIdx.x;
    const float4* b4 = (const float4*)(x + (size_t)bg * CPG * NP);
    int t = threadIdx.x;
    float s = 0.f, sq = 0.f;
    #pragma unroll
    for (int i = 0; i < 32; ++i) {
        float4 v = b4[t + i * 256];
        s  += v.x + v.y + v.z + v.w;
        sq += v.x*v.x + v.y*v.y + v.z*v.z + v.w*v.w;
    }
    for (int off = 32; off; off >>= 1) { s += __shfl_down(s, off); sq += __shfl_down(sq, off); }
    __shared__ float ss[4], ssq[4];
    int wid = t >> 6, lane = t & 63;
    if (lane == 0) { ss[wid] = s; ssq[wid] = sq; }
    __syncthreads();
    if (t == 0) {
        float S  = ss[0] + ss[1] + ss[2] + ss[3];
        float SQ = ssq[0] + ssq[1] + ssq[2] + ssq[3];
        const float inv = 1.f / (float)(CPG * NP);
        float m = S * inv;
        float var = SQ * inv - m * m;
        mu[bg] = m;
        rstd[bg] = rsqrtf(var + GEPS);
    }
}

// ===================== GN1 -> per (b,c) affine coefs =====================
__global__ void gn1_coefs_kernel(const float* __restrict__ mu, const float* __restrict__ rstd,
                                 const float* __restrict__ w, const float* __restrict__ bias,
                                 float* __restrict__ ac, float* __restrict__ dc) {
    int i = blockIdx.x * 256 + threadIdx.x;
    if (i >= NB * NC) return;
    int b = i / NC, c = i % NC;
    int g = c / CPG;
    float m = mu[b * NG + g], r = rstd[b * NG + g];
    float a = r * w[c];
    ac[i] = a;
    dc[i] = bias[c] - m * a;
}

// ===================== split qkv_w -> bf16 hi/lo (layout unchanged [1536][256]) ==========
__global__ void wsplit_kernel(const float* __restrict__ w, ushort* __restrict__ wh,
                              ushort* __restrict__ wl) {
    int i = blockIdx.x * 256 + threadIdx.x;    // 98304 float4
    float4 v = ((const float4*)w)[i];
    uint h, l;
    ushort4 hv, lv;
    split2(v.x, h, l); hv.x = (ushort)h; lv.x = (ushort)l;
    split2(v.y, h, l); hv.y = (ushort)h; lv.y = (ushort)l;
    split2(v.z, h, l); hv.z = (ushort)h; lv.z = (ushort)l;
    split2(v.w, h, l); hv.w = (ushort)h; lv.w = (ushort)l;
    ((ushort4*)wh)[i] = hv;
    ((ushort4*)wl)[i] = lv;
}

// ===================== x -> GN1-affine -> transpose [p][c] -> bf16 hi/lo ==========
// grid (NP/64, NC/64, CB), block 256
__global__ __launch_bounds__(256) void xsplit_kernel(const float* __restrict__ x,
                                                     const float* __restrict__ ac,
                                                     const float* __restrict__ dc,
                                                     ushort* __restrict__ xTh,
                                                     ushort* __restrict__ xTl, int b0) {
    int z = blockIdx.z, bglob = b0 + z;
    int p0 = blockIdx.x * 64, c0 = blockIdx.y * 64;
    const float* xb = x + (size_t)bglob * NC * NP;
    __shared__ float T[64][68];
    int t = threadIdx.x;
    #pragma unroll
    for (int j = 0; j < 4; ++j) {
        int idx = t + j * 256;              // 1024 float4
        int r = idx >> 4, c4 = idx & 15;
        float4 v = *(const float4*)(xb + (size_t)(c0 + r) * NP + p0 + c4 * 4);
        float a = ac[bglob * NC + c0 + r], d = dc[bglob * NC + c0 + r];
        v.x = fmaf(v.x, a, d); v.y = fmaf(v.y, a, d);
        v.z = fmaf(v.z, a, d); v.w = fmaf(v.w, a, d);
        *(float4*)&T[r][c4 * 4] = v;
    }
    __syncthreads();
    int p = t & 63, q4 = t >> 6;            // 4 groups of 16 channels
    size_t ob = ((size_t)z * NP + p0 + p) * NC + c0 + q4 * 16;
    #pragma unroll
    for (int blk = 0; blk < 2; ++blk) {     // 2 x 8 channels
        uint4 uh, ul;
        uint* ph = (uint*)&uh; uint* pl = (uint*)&ul;
        #pragma unroll
        for (int i = 0; i < 4; ++i) {
            int c = q4 * 16 + blk * 8 + i * 2;
            uint h0, l0, h1, l1;
            split2(T[c][p], h0, l0);
            split2(T[c + 1][p], h1, l1);
            ph[i] = h0 | (h1 << 16);
            pl[i] = l0 | (l1 << 16);
        }
        *(uint4*)(xTh + ob + blk * 8) = uh;
        *(uint4*)(xTl + ob + blk * 8) = ul;
    }
}

// ===================== split-bf16 MFMA GEMM ==========
// C[z][m][n] = sum_k A[z][m][k]*B[z][n][k]  (A,B bf16 hi/lo, [.][k] k-contig), C fp32 [m][NP]
// tile 128x128, BK=32, 4 waves (2x2 of 64x64)
template <bool BIAS>
__global__ __launch_bounds__(256) void gemm_mfma(
        const ushort* __restrict__ Ahg, const ushort* __restrict__ Alg,
        const ushort* __restrict__ Bhg, const ushort* __restrict__ Blg,
        const float* __restrict__ bias, float* __restrict__ Cg,
        int K, size_t strideA, size_t strideB, size_t strideC) {
    int z = blockIdx.z;
    const ushort* Ah = Ahg + strideA * z;
    const ushort* Al = Alg + strideA * z;
    const ushort* Bh = Bhg + strideB * z;
    const ushort* Bl = Blg + strideB * z;
    float* C = Cg + strideC * z;

    __shared__ ushort Ah_s[4][128][8];
    __shared__ ushort Al_s[4][128][8];
    __shared__ ushort Bh_s[4][128][8];
    __shared__ ushort Bl_s[4][128][8];

    const int t = threadIdx.x;
    const int w = t >> 6, l = t & 63;
    const int wr = w >> 1, wc = w & 1;
    const int m0 = blockIdx.y * 128, n0 = blockIdx.x * 128;
    const int l15 = l & 15, kb = l >> 4;

    f32x4 acc[4][4];
    #pragma unroll
    for (int i = 0; i < 4; ++i)
        #pragma unroll
        for (int j = 0; j < 4; ++j)
            acc[i][j] = (f32x4){0.f, 0.f, 0.f, 0.f};

    for (int k0 = 0; k0 < K; k0 += 32) {
        #pragma unroll
        for (int j = 0; j < 2; ++j) {
            int idx = t + j * 256;          // 512 = 128 rows x 4 k-subblocks
            int m = idx & 127, s = idx >> 7;
            size_t goA = (size_t)(m0 + m) * K + k0 + s * 8;
            size_t goB = (size_t)(n0 + m) * K + k0 + s * 8;
            *(uint4*)&Ah_s[s][m][0] = *(const uint4*)(Ah + goA);
            *(uint4*)&Al_s[s][m][0] = *(const uint4*)(Al + goA);
            *(uint4*)&Bh_s[s][m][0] = *(const uint4*)(Bh + goB);
            *(uint4*)&Bl_s[s][m][0] = *(const uint4*)(Bl + goB);
        }
        __syncthreads();
        bf16x8 ah[4], al[4];
        #pragma unroll
        for (int fi = 0; fi < 4; ++fi) {
            int m_loc = wr * 64 + fi * 16 + l15;
            ah[fi] = *(const bf16x8*)&Ah_s[kb][m_loc][0];
            al[fi] = *(const bf16x8*)&Al_s[kb][m_loc][0];
        }
        #pragma unroll
        for (int fj = 0; fj < 4; ++fj) {
            int n_loc = wc * 64 + fj * 16 + l15;
            bf16x8 bh = *(const bf16x8*)&Bh_s[kb][n_loc][0];
            bf16x8 bl = *(const bf16x8*)&Bl_s[kb][n_loc][0];
            #pragma unroll
            for (int fi = 0; fi < 4; ++fi) {
                acc[fi][fj] = MFMA_BF16(ah[fi], bh, acc[fi][fj]);
                acc[fi][fj] = MFMA_BF16(al[fi], bh, acc[fi][fj]);
                acc[fi][fj] = MFMA_BF16(ah[fi], bl, acc[fi][fj]);
            }
        }
        __syncthreads();
    }
    #pragma unroll
    for (int fi = 0; fi < 4; ++fi) {
        int mbase = m0 + wr * 64 + fi * 16 + (l >> 4) * 4;
        #pragma unroll
        for (int fj = 0; fj < 4; ++fj) {
            int n = n0 + wc * 64 + fj * 16 + l15;
            #pragma unroll
            for (int r = 0; r < 4; ++r) {
                float v = acc[fi][fj][r];
                if (BIAS) v += bias[mbase + r];
                C[(size_t)(mbase + r) * NP + n] = v;
            }
        }
    }
}

// ===================== ksum: sum_p exp(K[row][p]) per (z,row) ==========
__global__ __launch_bounds__(256) void ksum_kernel(const float* __restrict__ qkvb,
                                                   float* __restrict__ ksum) {
    int r = blockIdx.x, z = blockIdx.y;
    const float4* row = (const float4*)(qkvb + (size_t)z * OC3 * NP + (size_t)(HID + r) * NP);
    int t = threadIdx.x;
    float s = 0.f;
    #pragma unroll
    for (int i = 0; i < 4; ++i) {
        float4 v = row[t + i * 256];
        s += __expf(v.x) + __expf(v.y) + __expf(v.z) + __expf(v.w);
    }
    for (int off = 32; off; off >>= 1) s += __shfl_down(s, off);
    __shared__ float ss[4];
    int wid = t >> 6, lane = t & 63;
    if (lane == 0) ss[wid] = s;
    __syncthreads();
    if (t == 0) ksum[z * HID + r] = ss[0] + ss[1] + ss[2] + ss[3];
}

// ===================== softmax-q + transpose -> qsT bf16 hi/lo [z][p][hid] ==========
// grid (NP/64, 4 head-pairs, CB), block 128
__global__ __launch_bounds__(128) void smqT_kernel(const float* __restrict__ qkvb,
                                                   ushort* __restrict__ qsTh,
                                                   ushort* __restrict__ qsTl) {
    int z = blockIdx.z, p0 = blockIdx.x * 64, hp = blockIdx.y;
    const float* Qb = qkvb + (size_t)z * OC3 * NP + (size_t)hp * 128 * NP;
    __shared__ float T[128][68];
    int t = threadIdx.x;
    #pragma unroll
    for (int j = 0; j < 16; ++j) {
        int idx = t + j * 128;              // 2048 float4
        int r = idx >> 4, c4 = idx & 15;
        float4 v = *(const float4*)(Qb + (size_t)r * NP + p0 + c4 * 4);
        *(float4*)&T[r][c4 * 4] = v;
    }
    __syncthreads();
    int p = t & 63, hh = t >> 6;            // one (p, head) per thread
    int cb = hh * 64;
    float s = 0.f;
    #pragma unroll
    for (int f = 0; f < 64; ++f) s += __expf(T[cb + f][p]);
    float inv = 0.125f / s;
    size_t ob = ((size_t)z * NP + p0 + p) * HID + hp * 128 + hh * 64;
    #pragma unroll
    for (int blk = 0; blk < 8; ++blk) {
        uint4 uh, ul;
        uint* ph = (uint*)&uh; uint* pl = (uint*)&ul;
        #pragma unroll
        for (int i = 0; i < 4; ++i) {
            int f = blk * 8 + i * 2;
            float v0 = __expf(T[cb + f][p]) * inv;
            float v1 = __expf(T[cb + f + 1][p]) * inv;
            uint h0, l0, h1, l1;
            split2(v0, h0, l0);
            split2(v1, h1, l1);
            ph[i] = h0 | (h1 << 16);
            pl[i] = l0 | (l1 << 16);
        }
        *(uint4*)(qsTh + ob + blk * 8) = uh;
        *(uint4*)(qsTl + ob + blk * 8) = ul;
    }
}

// ===================== context partials: exp(K)*V^T, 16 p-splits ==========
// grid (16, NHD, CB), block 256
__global__ __launch_bounds__(256) void context_kernel(const float* __restrict__ qkvb,
                                                      float* __restrict__ ctxp, int CB) {
    int s = blockIdx.x, h = blockIdx.y, z = blockIdx.z;
    const float* kbase = qkvb + (size_t)z*OC3*NP + (size_t)(HID   + h*FD)*NP + s*256;
    const float* vbase = qkvb + (size_t)z*OC3*NP + (size_t)(2*HID + h*FD)*NP + s*256;
    __shared__ float Ks[64][68];
    __shared__ float Vs[64][68];
    int t = threadIdx.x;
    int tx = t & 15, ty = t >> 4;
    float acc[4][4] = {};
    for (int p0 = 0; p0 < 256; p0 += 64) {
        #pragma unroll
        for (int j = 0; j < 4; ++j) {
            int idx = t + j * 256;          // 1024 float4
            int r = idx >> 4, c4 = idx & 15;
            float4 kv = *(const float4*)(kbase + (size_t)r * NP + p0 + c4 * 4);
            kv.x = __expf(kv.x); kv.y = __expf(kv.y);
            kv.z = __expf(kv.z); kv.w = __expf(kv.w);
            *(float4*)&Ks[r][c4 * 4] = kv;
            *(float4*)&Vs[r][c4 * 4] = *(const float4*)(vbase + (size_t)r * NP + p0 + c4 * 4);
        }
        __syncthreads();
        #pragma unroll
        for (int pp = 0; pp < 64; pp += 4) {
            float4 a[4], bv[4];
            #pragma unroll
            for (int i = 0; i < 4; ++i) a[i]  = *(float4*)&Ks[ty * 4 + i][pp];
            #pragma unroll
            for (int j = 0; j < 4; ++j) bv[j] = *(float4*)&Vs[tx * 4 + j][pp];
            #pragma unroll
            for (int i = 0; i < 4; ++i)
                #pragma unroll
                for (int j = 0; j < 4; ++j)
                    acc[i][j] += a[i].x*bv[j].x + a[i].y*bv[j].y + a[i].z*bv[j].z + a[i].w*bv[j].w;
        }
        __syncthreads();
    }
    float* outp = ctxp + ((size_t)(s * CB + z) * NHD + h) * FD * FD;
    #pragma unroll
    for (int i = 0; i < 4; ++i)
        *(float4*)(outp + (size_t)(ty * 4 + i) * FD + tx * 4) = *(float4*)&acc[i][0];
}

__global__ void ctx_reduce_kernel(const float* __restrict__ ctxp, float* __restrict__ ctx,
                                  int n4) {
    int i = blockIdx.x * 256 + threadIdx.x;       // n4 = CB*8192 float4
    if (i >= n4) return;
    const float4* p = (const float4*)ctxp;
    float4 r = {0.f, 0.f, 0.f, 0.f};
    #pragma unroll
    for (int s = 0; s < 16; ++s) {
        float4 a = p[(size_t)s * n4 + i];
        r.x += a.x; r.y += a.y; r.z += a.z; r.w += a.w;
    }
    ((float4*)ctx)[i] = r;
}

// ===================== fold: W2[z][o][hf] = (sum_e out_w[o][he]*ctx[z,h,f,e]) / ksum ==========
// grid (NHD, CB), block 256
__global__ __launch_bounds__(256) void fold_kernel(const float* __restrict__ out_w,
                                                   const float* __restrict__ ctx,
                                                   const float* __restrict__ ksum,
                                                   ushort* __restrict__ w2h,
                                                   ushort* __restrict__ w2l) {
    int h = blockIdx.x, z = blockIdx.y;
    __shared__ float Cs[FD][FD];
    int t = threadIdx.x;
    const float* cbase = ctx + ((size_t)z * NHD + h) * FD * FD;
    #pragma unroll
    for (int j = 0; j < 16; ++j) ((float*)Cs)[t + j * 256] = cbase[t + j * 256];
    __syncthreads();
    float wr[64];
    const float* wrow = out_w + (size_t)t * HID + h * FD;
    #pragma unroll
    for (int e = 0; e < 64; ++e) wr[e] = wrow[e];
    size_t ob = ((size_t)z * NC + t) * HID + h * FD;
    for (int f = 0; f < 64; ++f) {
        float sacc = 0.f;
        #pragma unroll
        for (int e = 0; e < 64; ++e) sacc = fmaf(wr[e], Cs[f][e], sacc);
        float v = sacc / ksum[z * HID + h * FD + f];
        uint hb, lb;
        split2(v, hb, lb);
        w2h[ob + f] = (ushort)hb;
        w2l[ob + f] = (ushort)lb;
    }
}

// ===================== GN2 apply in-place on d_out =====================
__global__ void gn2_apply_kernel(float* __restrict__ out, const float* __restrict__ mu,
                                 const float* __restrict__ rstd, const float* __restrict__ w,
                                 const float* __restrict__ bias) {
    int i = blockIdx.x * 256 + threadIdx.x;
    float4* p = (float4*)out;
    float4 v = p[i];
    size_t e0 = (size_t)i * 4;
    int cidx = (int)((e0 / NP) % NC);
    int bg   = (int)(e0 / ((size_t)CPG * NP));
    float m = mu[bg], r = rstd[bg];
    float a = r * w[cidx];
    float d = bias[cidx] - m * a;
    v.x = fmaf(v.x, a, d); v.y = fmaf(v.y, a, d);
    v.z = fmaf(v.z, a, d); v.w = fmaf(v.w, a, d);
    p[i] = v;
}

// ===================== launch =====================
extern "C" void kernel_launch(void* const* d_in, const int* in_sizes, int n_in,
                              void* d_out, int out_size, void* d_ws, size_t ws_size,
                              hipStream_t stream) {
    const float* x     = (const float*)d_in[0];
    const float* gn1_w = (const float*)d_in[1];
    const float* gn1_b = (const float*)d_in[2];
    const float* qkv_w = (const float*)d_in[3];
    const float* out_w = (const float*)d_in[4];
    const float* out_b = (const float*)d_in[5];
    const float* gn2_w = (const float*)d_in[6];
    const float* gn2_b = (const float*)d_in[7];
    float* out = (float*)d_out;

    // ---- pick chunk size CB by workspace budget ----
    auto need = [](int cb) -> size_t {
        size_t tot = 0;
        auto al = [&](size_t b) { tot = (tot + b + 255) & ~(size_t)255; };
        al((size_t)cb * OC3 * NP * 4);                         // qkvb
        al((size_t)cb * NP * NC * 2); al((size_t)cb * NP * NC * 2);   // xT h/l
        al((size_t)cb * NP * HID * 2); al((size_t)cb * NP * HID * 2); // qsT h/l
        al((size_t)16 * cb * NHD * FD * FD * 4);               // ctxp
        al((size_t)cb * NHD * FD * FD * 4);                    // ctx
        al((size_t)cb * NC * HID * 2); al((size_t)cb * NC * HID * 2); // w2 h/l
        al((size_t)OC3 * NC * 2); al((size_t)OC3 * NC * 2);    // Wq h/l
        al((size_t)cb * HID * 4);                              // ksum
        al((size_t)2 * NB * NC * 4);                           // ac,dc
        al((size_t)4 * NB * NG * 4);                           // stats
        return tot;
    };
    int CB = 1;
    {
        const int cands[4] = {16, 8, 4, 2};
        for (int i = 0; i < 4; ++i) if (need(cands[i]) <= ws_size) { CB = cands[i]; break; }
    }

    // ---- carve workspace (same order as need()) ----
    char* base = (char*)d_ws;
    size_t off = 0;
    auto carve = [&](size_t b) -> char* {
        char* p = base + off;
        off = (off + b + 255) & ~(size_t)255;
        return p;
    };
    float*  qkvb = (float*) carve((size_t)CB * OC3 * NP * 4);
    ushort* xTh  = (ushort*)carve((size_t)CB * NP * NC * 2);
    ushort* xTl  = (ushort*)carve((size_t)CB * NP * NC * 2);
    ushort* qsTh = (ushort*)carve((size_t)CB * NP * HID * 2);
    ushort* qsTl = (ushort*)carve((size_t)CB * NP * HID * 2);
    float*  ctxp = (float*) carve((size_t)16 * CB * NHD * FD * FD * 4);
    float*  ctx  = (float*) carve((size_t)CB * NHD * FD * FD * 4);
    ushort* w2h  = (ushort*)carve((size_t)CB * NC * HID * 2);
    ushort* w2l  = (ushort*)carve((size_t)CB * NC * HID * 2);
    ushort* Wqh  = (ushort*)carve((size_t)OC3 * NC * 2);
    ushort* Wql  = (ushort*)carve((size_t)OC3 * NC * 2);
    float*  ksum = (float*) carve((size_t)CB * HID * 4);
    float*  ac   = (float*) carve((size_t)2 * NB * NC * 4);
    float*  dc   = ac + (size_t)NB * NC;
    float*  mu1  = (float*) carve((size_t)4 * NB * NG * 4);
    float*  rstd1 = mu1 + NB * NG;
    float*  mu2   = rstd1 + NB * NG;
    float*  rstd2 = mu2 + NB * NG;

    // 1. GN1 stats + affine coefs + weight split
    gn_stats_kernel<<<NB * NG, 256, 0, stream>>>(x, mu1, rstd1);
    gn1_coefs_kernel<<<16, 256, 0, stream>>>(mu1, rstd1, gn1_w, gn1_b, ac, dc);
    wsplit_kernel<<<OC3 * NC / 1024, 256, 0, stream>>>(qkv_w, Wqh, Wql);

    // 2. chunked pipeline
    for (int b0 = 0; b0 < NB; b0 += CB) {
        xsplit_kernel<<<dim3(NP / 64, NC / 64, CB), 256, 0, stream>>>(x, ac, dc, xTh, xTl, b0);
        gemm_mfma<false><<<dim3(NP / 128, OC3 / 128, CB), 256, 0, stream>>>(
            Wqh, Wql, xTh, xTl, nullptr, qkvb, NC,
            (size_t)0, (size_t)NP * NC, (size_t)OC3 * NP);
        ksum_kernel<<<dim3(HID, CB), 256, 0, stream>>>(qkvb, ksum);
        smqT_kernel<<<dim3(NP / 64, 4, CB), 128, 0, stream>>>(qkvb, qsTh, qsTl);
        context_kernel<<<dim3(16, NHD, CB), 256, 0, stream>>>(qkvb, ctxp, CB);
        ctx_reduce_kernel<<<CB * 32, 256, 0, stream>>>(ctxp, ctx, CB * 8192);
        fold_kernel<<<dim3(NHD, CB), 256, 0, stream>>>(out_w, ctx, ksum, w2h, w2l);
        gemm_mfma<true><<<dim3(NP / 128, NC / 128, CB), 256, 0, stream>>>(
            w2h, w2l, qsTh, qsTl, out_b, out + (size_t)b0 * NC * NP, HID,
            (size_t)NC * HID, (size_t)NP * HID, (size_t)NC * NP);
    }

    // 3. GN2
    gn_stats_kernel<<<NB * NG, 256, 0, stream>>>(out, mu2, rstd2);
    gn2_apply_kernel<<<16384, 256, 0, stream>>>(out, mu2, rstd2, gn2_w, gn2_b);
}

// Round 5
// 659.057 us; speedup vs baseline: 5.3203x; 1.4694x over previous
//
#include <hip/hip_runtime.h>
#include <math.h>

#define NB   16
#define NC   256
#define NP   4096
#define NHD  8
#define FD   64
#define HID  512
#define OC3  1536
#define NG   32
#define CPG  8
#define GEPS 1e-5f

typedef __attribute__((ext_vector_type(8))) short bf16x8;
typedef __attribute__((ext_vector_type(4))) float f32x4;

#define MFMA_BF16(a, b, c) __builtin_amdgcn_mfma_f32_16x16x32_bf16(a, b, c, 0, 0, 0)

__device__ __forceinline__ uint bf16_rne(float v) {
    uint u = __float_as_uint(v);
    return (u + 0x7FFFu + ((u >> 16) & 1u)) >> 16;
}
__device__ __forceinline__ void split2(float v, uint& h, uint& l) {
    h = bf16_rne(v);
    l = bf16_rne(v - __uint_as_float(h << 16));
}
__device__ __forceinline__ void gload16(const void* g, void* l) {
    __builtin_amdgcn_global_load_lds(
        (const __attribute__((address_space(1))) void*)g,
        (__attribute__((address_space(3))) void*)l, 16, 0, 0);
}

// ===================== GroupNorm stats: one block per (b,g) =====================
__global__ __launch_bounds__(256) void gn_stats_kernel(const float* __restrict__ x,
                                                       float* __restrict__ mu,
                                                       float* __restrict__ rstd) {
    int bg = blockIdx.x;
    const float4* b4 = (const float4*)(x + (size_t)bg * CPG * NP);
    int t = threadIdx.x;
    float s = 0.f, sq = 0.f;
    #pragma unroll
    for (int i = 0; i < 32; ++i) {
        float4 v = b4[t + i * 256];
        s  += v.x + v.y + v.z + v.w;
        sq += v.x*v.x + v.y*v.y + v.z*v.z + v.w*v.w;
    }
    for (int off = 32; off; off >>= 1) { s += __shfl_down(s, off); sq += __shfl_down(sq, off); }
    __shared__ float ss[4], ssq[4];
    int wid = t >> 6, lane = t & 63;
    if (lane == 0) { ss[wid] = s; ssq[wid] = sq; }
    __syncthreads();
    if (t == 0) {
        float S  = ss[0] + ss[1] + ss[2] + ss[3];
        float SQ = ssq[0] + ssq[1] + ssq[2] + ssq[3];
        const float inv = 1.f / (float)(CPG * NP);
        float m = S * inv;
        float var = SQ * inv - m * m;
        mu[bg] = m;
        rstd[bg] = rsqrtf(var + GEPS);
    }
}

// ===================== GN1 -> per (b,c) affine coefs =====================
__global__ void gn1_coefs_kernel(const float* __restrict__ mu, const float* __restrict__ rstd,
                                 const float* __restrict__ w, const float* __restrict__ bias,
                                 float* __restrict__ ac, float* __restrict__ dc) {
    int i = blockIdx.x * 256 + threadIdx.x;
    if (i >= NB * NC) return;
    int b = i / NC, c = i % NC;
    int g = c / CPG;
    float m = mu[b * NG + g], r = rstd[b * NG + g];
    float a = r * w[c];
    ac[i] = a;
    dc[i] = bias[c] - m * a;
}

// ===================== split qkv_w -> bf16 hi/lo ==========
__global__ void wsplit_kernel(const float* __restrict__ w, ushort* __restrict__ wh,
                              ushort* __restrict__ wl) {
    int i = blockIdx.x * 256 + threadIdx.x;    // 98304 float4
    float4 v = ((const float4*)w)[i];
    uint h, l;
    ushort4 hv, lv;
    split2(v.x, h, l); hv.x = (ushort)h; lv.x = (ushort)l;
    split2(v.y, h, l); hv.y = (ushort)h; lv.y = (ushort)l;
    split2(v.z, h, l); hv.z = (ushort)h; lv.z = (ushort)l;
    split2(v.w, h, l); hv.w = (ushort)h; lv.w = (ushort)l;
    ((ushort4*)wh)[i] = hv;
    ((ushort4*)wl)[i] = lv;
}

// ===================== x -> GN1-affine -> transpose [p][c] -> bf16 hi/lo ==========
__global__ __launch_bounds__(256) void xsplit_kernel(const float* __restrict__ x,
                                                     const float* __restrict__ ac,
                                                     const float* __restrict__ dc,
                                                     ushort* __restrict__ xTh,
                                                     ushort* __restrict__ xTl, int b0) {
    int z = blockIdx.z, bglob = b0 + z;
    int p0 = blockIdx.x * 64, c0 = blockIdx.y * 64;
    const float* xb = x + (size_t)bglob * NC * NP;
    __shared__ float T[64][68];
    int t = threadIdx.x;
    #pragma unroll
    for (int j = 0; j < 4; ++j) {
        int idx = t + j * 256;
        int r = idx >> 4, c4 = idx & 15;
        float4 v = *(const float4*)(xb + (size_t)(c0 + r) * NP + p0 + c4 * 4);
        float a = ac[bglob * NC + c0 + r], d = dc[bglob * NC + c0 + r];
        v.x = fmaf(v.x, a, d); v.y = fmaf(v.y, a, d);
        v.z = fmaf(v.z, a, d); v.w = fmaf(v.w, a, d);
        *(float4*)&T[r][c4 * 4] = v;
    }
    __syncthreads();
    int p = t & 63, q4 = t >> 6;
    size_t ob = ((size_t)z * NP + p0 + p) * NC + c0 + q4 * 16;
    #pragma unroll
    for (int blk = 0; blk < 2; ++blk) {
        uint4 uh, ul;
        uint* ph = (uint*)&uh; uint* pl = (uint*)&ul;
        #pragma unroll
        for (int i = 0; i < 4; ++i) {
            int c = q4 * 16 + blk * 8 + i * 2;
            uint h0, l0, h1, l1;
            split2(T[c][p], h0, l0);
            split2(T[c + 1][p], h1, l1);
            ph[i] = h0 | (h1 << 16);
            pl[i] = l0 | (l1 << 16);
        }
        *(uint4*)(xTh + ob + blk * 8) = uh;
        *(uint4*)(xTl + ob + blk * 8) = ul;
    }
}

// ===================== split-bf16 MFMA GEMM, global_load_lds staging ==========
// C[z][m][n] = sum_k A[z][m][k]*B[z][n][k]; MODE 0: fp32 C + bias; MODE 1: fused qkv epilogue
template <int MODE>
__global__ __launch_bounds__(256) void gemm_mfma(
        const ushort* __restrict__ Ahg, const ushort* __restrict__ Alg,
        const ushort* __restrict__ Bhg, const ushort* __restrict__ Blg,
        const float* __restrict__ bias, float* __restrict__ Cg,
        ushort* __restrict__ qsTh, ushort* __restrict__ qsTl,
        uint* __restrict__ ekp, uint* __restrict__ vp,
        float* __restrict__ kspart,
        int K, size_t strideA, size_t strideB, size_t strideC) {
    __shared__ __align__(16) char smem[33280];   // staging 4x8KB; reused as Tq u32[64][130]
    const int z = blockIdx.z;
    const ushort* Ah = Ahg + strideA * z;
    const ushort* Al = Alg + strideA * z;
    const ushort* Bh = Bhg + strideB * z;
    const ushort* Bl = Blg + strideB * z;

    const int t = threadIdx.x;
    const int w = t >> 6, l = t & 63;
    const int wr = w >> 1, wc = w & 1;
    const int m0 = blockIdx.y * 128, n0 = blockIdx.x * 128;
    const int l15 = l & 15, kb = l >> 4;

    f32x4 acc[4][4];
    #pragma unroll
    for (int i = 0; i < 4; ++i)
        #pragma unroll
        for (int j = 0; j < 4; ++j)
            acc[i][j] = (f32x4){0.f, 0.f, 0.f, 0.f};

    for (int k0 = 0; k0 < K; k0 += 32) {
        #pragma unroll
        for (int j = 0; j < 2; ++j) {
            int idx = t + j * 256;          // 512 slots = 128 rows x 4 k-subblocks
            int m = idx & 127, s = idx >> 7;
            size_t goA = (size_t)(m0 + m) * K + k0 + s * 8;
            size_t goB = (size_t)(n0 + m) * K + k0 + s * 8;
            int lo = idx * 16;
            gload16(Ah + goA, smem + lo);
            gload16(Al + goA, smem + 8192 + lo);
            gload16(Bh + goB, smem + 16384 + lo);
            gload16(Bl + goB, smem + 24576 + lo);
        }
        __syncthreads();
        bf16x8 ah[4], al[4];
        #pragma unroll
        for (int fi = 0; fi < 4; ++fi) {
            int off = (kb * 128 + wr * 64 + fi * 16 + l15) * 16;
            ah[fi] = *(const bf16x8*)(smem + off);
            al[fi] = *(const bf16x8*)(smem + 8192 + off);
        }
        #pragma unroll
        for (int fj = 0; fj < 4; ++fj) {
            int off = (kb * 128 + wc * 64 + fj * 16 + l15) * 16;
            bf16x8 bh = *(const bf16x8*)(smem + 16384 + off);
            bf16x8 bl = *(const bf16x8*)(smem + 24576 + off);
            #pragma unroll
            for (int fi = 0; fi < 4; ++fi) {
                acc[fi][fj] = MFMA_BF16(ah[fi], bh, acc[fi][fj]);
                acc[fi][fj] = MFMA_BF16(al[fi], bh, acc[fi][fj]);
                acc[fi][fj] = MFMA_BF16(ah[fi], bl, acc[fi][fj]);
            }
        }
        __syncthreads();
    }

    if (MODE == 0) {
        float* C = Cg + strideC * z;
        #pragma unroll
        for (int fi = 0; fi < 4; ++fi) {
            int mbase = m0 + wr * 64 + fi * 16 + kb * 4;
            #pragma unroll
            for (int fj = 0; fj < 4; ++fj) {
                int n = n0 + wc * 64 + fj * 16 + l15;
                #pragma unroll
                for (int r = 0; r < 4; ++r)
                    C[(size_t)(mbase + r) * NP + n] = acc[fi][fj][r] + bias[mbase + r];
            }
        }
        return;
    }

    // ---------- MODE 1: fused qkv epilogue ----------
    int tile = m0 >> 7;     // 0..3 Q, 4..7 K, 8..11 V
    if (tile < 4) {
        // Q: per-head feature softmax (64 rows per wave == one head), transpose, bf16 split
        uint* Tq = (uint*)smem;    // [64][130]
        #pragma unroll
        for (int half = 0; half < 2; ++half) {
            if (wc == half) {
                #pragma unroll
                for (int fj = 0; fj < 4; ++fj) {
                    float ex[16];
                    float cs = 0.f;
                    #pragma unroll
                    for (int fi = 0; fi < 4; ++fi)
                        #pragma unroll
                        for (int r = 0; r < 4; ++r) {
                            float e = __expf(acc[fi][fj][r]);
                            ex[fi * 4 + r] = e;
                            cs += e;
                        }
                    cs += __shfl_xor(cs, 16);
                    cs += __shfl_xor(cs, 32);
                    float inv = 0.125f / cs;
                    int p_loc = fj * 16 + l15;
                    #pragma unroll
                    for (int fi = 0; fi < 4; ++fi)
                        #pragma unroll
                        for (int r = 0; r < 4; ++r) {
                            uint hb, lb;
                            split2(ex[fi * 4 + r] * inv, hb, lb);
                            Tq[p_loc * 130 + wr * 64 + fi * 16 + kb * 4 + r] = (hb << 16) | lb;
                        }
                }
            }
            __syncthreads();
            int p = t >> 2, seg = t & 3;
            size_t ob = ((size_t)z * NP + n0 + half * 64 + p) * HID + m0 + seg * 32;
            #pragma unroll
            for (int c = 0; c < 4; ++c) {
                uint4 H, L;
                uint* hp = (uint*)&H; uint* lp = (uint*)&L;
                #pragma unroll
                for (int i = 0; i < 4; ++i) {
                    uint u0 = Tq[p * 130 + seg * 32 + c * 8 + 2 * i];
                    uint u1 = Tq[p * 130 + seg * 32 + c * 8 + 2 * i + 1];
                    hp[i] = (u0 >> 16) | (u1 & 0xffff0000u);
                    lp[i] = (u0 & 0xffffu) | (u1 << 16);
                }
                *(uint4*)(qsTh + ob + c * 8) = H;
                *(uint4*)(qsTl + ob + c * 8) = L;
            }
            __syncthreads();
        }
    } else {
        bool isK = tile < 8;
        uint* dst = (isK ? ekp : vp) + (size_t)z * HID * NP;
        int rbase = m0 - (isK ? 512 : 1024) + wr * 64;
        #pragma unroll
        for (int fi = 0; fi < 4; ++fi) {
            #pragma unroll
            for (int r = 0; r < 4; ++r) {
                int row = rbase + fi * 16 + kb * 4 + r;
                float rs = 0.f;
                #pragma unroll
                for (int fj = 0; fj < 4; ++fj) {
                    float v = acc[fi][fj][r];
                    float e = isK ? __expf(v) : v;
                    rs += e;
                    uint hb, lb;
                    split2(e, hb, lb);
                    dst[(size_t)row * NP + n0 + wc * 64 + fj * 16 + l15] = (hb << 16) | lb;
                }
                if (isK) {
                    rs += __shfl_xor(rs, 1);
                    rs += __shfl_xor(rs, 2);
                    rs += __shfl_xor(rs, 4);
                    rs += __shfl_xor(rs, 8);
                    if (l15 == 0)
                        kspart[((size_t)z * HID + row) * 64 + blockIdx.x * 2 + wc] = rs;
                }
            }
        }
    }
}

// ===================== ksum reduce: 64 partials per (z,row) ==========
__global__ void ksum_reduce_kernel(const float* __restrict__ kspart,
                                   float* __restrict__ ksum, int n) {
    int i = blockIdx.x * 256 + threadIdx.x;
    if (i >= n) return;
    float s = 0.f;
    #pragma unroll
    for (int j = 0; j < 64; ++j) s += kspart[(size_t)i * 64 + j];
    ksum[i] = s;
}

// ===================== context = expK @ V^T per (z,h), MFMA, 4 p-slices ==========
// packed u32 inputs (hi<<16|lo bf16); 1 wave per block
__global__ __launch_bounds__(64) void context_mfma(const uint* __restrict__ ekp,
                                                   const uint* __restrict__ vp,
                                                   float* __restrict__ ctxp) {
    int s = blockIdx.x, hz = blockIdx.y;      // hz = z*NHD + h
    const uint* K0 = ekp + (size_t)hz * FD * NP + (size_t)s * 1024;
    const uint* V0 = vp  + (size_t)hz * FD * NP + (size_t)s * 1024;
    int l = threadIdx.x, l15 = l & 15, kb = l >> 4;
    f32x4 acc[4][4];
    #pragma unroll
    for (int i = 0; i < 4; ++i)
        #pragma unroll
        for (int j = 0; j < 4; ++j)
            acc[i][j] = (f32x4){0.f, 0.f, 0.f, 0.f};

    for (int p0 = 0; p0 < 1024; p0 += 32) {
        bf16x8 ah[4], al[4], bh[4], bl[4];
        #pragma unroll
        for (int fi = 0; fi < 4; ++fi) {
            const uint* srcK = K0 + (size_t)(fi * 16 + l15) * NP + p0 + kb * 8;
            const uint* srcV = V0 + (size_t)(fi * 16 + l15) * NP + p0 + kb * 8;
            uint ku[8], vu[8];
            *(uint4*)&ku[0] = *(const uint4*)srcK;
            *(uint4*)&ku[4] = *(const uint4*)(srcK + 4);
            *(uint4*)&vu[0] = *(const uint4*)srcV;
            *(uint4*)&vu[4] = *(const uint4*)(srcV + 4);
            bf16x8 kh, kl, vh, vl;
            #pragma unroll
            for (int i = 0; i < 8; ++i) {
                kh[i] = (short)(ku[i] >> 16); kl[i] = (short)(ku[i] & 0xffffu);
                vh[i] = (short)(vu[i] >> 16); vl[i] = (short)(vu[i] & 0xffffu);
            }
            ah[fi] = kh; al[fi] = kl; bh[fi] = vh; bl[fi] = vl;
        }
        #pragma unroll
        for (int fj = 0; fj < 4; ++fj)
            #pragma unroll
            for (int fi = 0; fi < 4; ++fi) {
                acc[fi][fj] = MFMA_BF16(ah[fi], bh[fj], acc[fi][fj]);
                acc[fi][fj] = MFMA_BF16(al[fi], bh[fj], acc[fi][fj]);
                acc[fi][fj] = MFMA_BF16(ah[fi], bl[fj], acc[fi][fj]);
            }
    }
    float* outp = ctxp + ((size_t)s * gridDim.y + hz) * FD * FD;
    #pragma unroll
    for (int fi = 0; fi < 4; ++fi)
        #pragma unroll
        for (int fj = 0; fj < 4; ++fj)
            #pragma unroll
            for (int r = 0; r < 4; ++r)
                outp[(size_t)(fi * 16 + kb * 4 + r) * FD + fj * 16 + l15] = acc[fi][fj][r];
}

__global__ void ctx_reduce_kernel(const float* __restrict__ ctxp, float* __restrict__ ctx,
                                  int n4) {
    int i = blockIdx.x * 256 + threadIdx.x;       // n4 = CB*8192 float4
    if (i >= n4) return;
    const float4* p = (const float4*)ctxp;
    float4 r = {0.f, 0.f, 0.f, 0.f};
    #pragma unroll
    for (int s = 0; s < 4; ++s) {
        float4 a = p[(size_t)s * n4 + i];
        r.x += a.x; r.y += a.y; r.z += a.z; r.w += a.w;
    }
    ((float4*)ctx)[i] = r;
}

// ===================== fold: W2[z][o][hf] = (sum_e out_w[o][he]*ctx[z,h,f,e]) / ksum ==========
__global__ __launch_bounds__(256) void fold_kernel(const float* __restrict__ out_w,
                                                   const float* __restrict__ ctx,
                                                   const float* __restrict__ ksum,
                                                   ushort* __restrict__ w2h,
                                                   ushort* __restrict__ w2l) {
    int h = blockIdx.x, z = blockIdx.y;
    __shared__ float Cs[FD][FD];
    int t = threadIdx.x;
    const float* cbase = ctx + ((size_t)z * NHD + h) * FD * FD;
    #pragma unroll
    for (int j = 0; j < 16; ++j) ((float*)Cs)[t + j * 256] = cbase[t + j * 256];
    __syncthreads();
    float wr[64];
    const float* wrow = out_w + (size_t)t * HID + h * FD;
    #pragma unroll
    for (int e = 0; e < 64; ++e) wr[e] = wrow[e];
    size_t ob = ((size_t)z * NC + t) * HID + h * FD;
    for (int f = 0; f < 64; ++f) {
        float sacc = 0.f;
        #pragma unroll
        for (int e = 0; e < 64; ++e) sacc = fmaf(wr[e], Cs[f][e], sacc);
        float v = sacc / ksum[(size_t)z * HID + h * FD + f];
        uint hb, lb;
        split2(v, hb, lb);
        w2h[ob + f] = (ushort)hb;
        w2l[ob + f] = (ushort)lb;
    }
}

// ===================== GN2 apply in-place on d_out =====================
__global__ void gn2_apply_kernel(float* __restrict__ out, const float* __restrict__ mu,
                                 const float* __restrict__ rstd, const float* __restrict__ w,
                                 const float* __restrict__ bias) {
    int i = blockIdx.x * 256 + threadIdx.x;
    float4* p = (float4*)out;
    float4 v = p[i];
    size_t e0 = (size_t)i * 4;
    int cidx = (int)((e0 / NP) % NC);
    int bg   = (int)(e0 / ((size_t)CPG * NP));
    float m = mu[bg], r = rstd[bg];
    float a = r * w[cidx];
    float d = bias[cidx] - m * a;
    v.x = fmaf(v.x, a, d); v.y = fmaf(v.y, a, d);
    v.z = fmaf(v.z, a, d); v.w = fmaf(v.w, a, d);
    p[i] = v;
}

// ===================== launch =====================
extern "C" void kernel_launch(void* const* d_in, const int* in_sizes, int n_in,
                              void* d_out, int out_size, void* d_ws, size_t ws_size,
                              hipStream_t stream) {
    const float* x     = (const float*)d_in[0];
    const float* gn1_w = (const float*)d_in[1];
    const float* gn1_b = (const float*)d_in[2];
    const float* qkv_w = (const float*)d_in[3];
    const float* out_w = (const float*)d_in[4];
    const float* out_b = (const float*)d_in[5];
    const float* gn2_w = (const float*)d_in[6];
    const float* gn2_b = (const float*)d_in[7];
    float* out = (float*)d_out;

    // ---- pick chunk size CB by workspace budget ----
    auto need = [](int cb) -> size_t {
        size_t tot = 0;
        auto al = [&](size_t b) { tot = (tot + b + 255) & ~(size_t)255; };
        al((size_t)cb * NP * NC * 2);  al((size_t)cb * NP * NC * 2);   // xT h/l
        al((size_t)cb * NP * HID * 2); al((size_t)cb * NP * HID * 2);  // qsT h/l
        al((size_t)cb * HID * NP * 4);                                 // ekp
        al((size_t)cb * HID * NP * 4);                                 // vp
        al((size_t)cb * HID * 64 * 4);                                 // kspart
        al((size_t)cb * HID * 4);                                      // ksum
        al((size_t)4 * cb * NHD * FD * FD * 4);                        // ctxp
        al((size_t)cb * NHD * FD * FD * 4);                            // ctx
        al((size_t)cb * NC * HID * 2); al((size_t)cb * NC * HID * 2);  // w2 h/l
        al((size_t)OC3 * NC * 2); al((size_t)OC3 * NC * 2);            // Wq h/l
        al((size_t)2 * NB * NC * 4);                                   // ac,dc
        al((size_t)4 * NB * NG * 4);                                   // stats
        return tot;
    };
    int CB = 1;
    {
        const int cands[5] = {16, 8, 4, 2, 1};
        for (int i = 0; i < 5; ++i) if (need(cands[i]) <= ws_size) { CB = cands[i]; break; }
    }

    // ---- carve workspace (same order as need()) ----
    char* base = (char*)d_ws;
    size_t off = 0;
    auto carve = [&](size_t b) -> char* {
        char* p = base + off;
        off = (off + b + 255) & ~(size_t)255;
        return p;
    };
    ushort* xTh  = (ushort*)carve((size_t)CB * NP * NC * 2);
    ushort* xTl  = (ushort*)carve((size_t)CB * NP * NC * 2);
    ushort* qsTh = (ushort*)carve((size_t)CB * NP * HID * 2);
    ushort* qsTl = (ushort*)carve((size_t)CB * NP * HID * 2);
    uint*   ekp  = (uint*)  carve((size_t)CB * HID * NP * 4);
    uint*   vp   = (uint*)  carve((size_t)CB * HID * NP * 4);
    float*  kspart = (float*)carve((size_t)CB * HID * 64 * 4);
    float*  ksum = (float*) carve((size_t)CB * HID * 4);
    float*  ctxp = (float*) carve((size_t)4 * CB * NHD * FD * FD * 4);
    float*  ctx  = (float*) carve((size_t)CB * NHD * FD * FD * 4);
    ushort* w2h  = (ushort*)carve((size_t)CB * NC * HID * 2);
    ushort* w2l  = (ushort*)carve((size_t)CB * NC * HID * 2);
    ushort* Wqh  = (ushort*)carve((size_t)OC3 * NC * 2);
    ushort* Wql  = (ushort*)carve((size_t)OC3 * NC * 2);
    float*  ac   = (float*) carve((size_t)2 * NB * NC * 4);
    float*  dc   = ac + (size_t)NB * NC;
    float*  mu1  = (float*) carve((size_t)4 * NB * NG * 4);
    float*  rstd1 = mu1 + NB * NG;
    float*  mu2   = rstd1 + NB * NG;
    float*  rstd2 = mu2 + NB * NG;

    // 1. GN1 stats + affine coefs + weight split
    gn_stats_kernel<<<NB * NG, 256, 0, stream>>>(x, mu1, rstd1);
    gn1_coefs_kernel<<<16, 256, 0, stream>>>(mu1, rstd1, gn1_w, gn1_b, ac, dc);
    wsplit_kernel<<<OC3 * NC / 1024, 256, 0, stream>>>(qkv_w, Wqh, Wql);

    // 2. chunked pipeline
    for (int b0 = 0; b0 < NB; b0 += CB) {
        xsplit_kernel<<<dim3(NP / 64, NC / 64, CB), 256, 0, stream>>>(x, ac, dc, xTh, xTl, b0);
        gemm_mfma<1><<<dim3(NP / 128, OC3 / 128, CB), 256, 0, stream>>>(
            Wqh, Wql, xTh, xTl, nullptr, nullptr,
            qsTh, qsTl, ekp, vp, kspart,
            NC, (size_t)0, (size_t)NP * NC, (size_t)0);
        ksum_reduce_kernel<<<CB * 2, 256, 0, stream>>>(kspart, ksum, CB * HID);
        context_mfma<<<dim3(4, CB * NHD), 64, 0, stream>>>(ekp, vp, ctxp);
        ctx_reduce_kernel<<<CB * 32, 256, 0, stream>>>(ctxp, ctx, CB * 8192);
        fold_kernel<<<dim3(NHD, CB), 256, 0, stream>>>(out_w, ctx, ksum, w2h, w2l);
        gemm_mfma<0><<<dim3(NP / 128, NC / 128, CB), 256, 0, stream>>>(
            w2h, w2l, qsTh, qsTl, out_b, out + (size_t)b0 * NC * NP,
            nullptr, nullptr, nullptr, nullptr, nullptr,
            HID, (size_t)NC * HID, (size_t)NP * HID, (size_t)NC * NP);
    }

    // 3. GN2
    gn_stats_kernel<<<NB * NG, 256, 0, stream>>>(out, mu2, rstd2);
    gn2_apply_kernel<<<16384, 256, 0, stream>>>(out, mu2, rstd2, gn2_w, gn2_b);
}